// Round 12
// baseline (892.296 us; speedup 1.0000x reference)
//
#include <hip/hip_runtime.h>
#include <math.h>

typedef unsigned short ushort_t;
typedef unsigned int uint_t;
typedef __bf16 bf16x4 __attribute__((ext_vector_type(4)));
typedef __bf16 bf16x8 __attribute__((ext_vector_type(8)));
typedef float f32x4 __attribute__((ext_vector_type(4)));

#define T_SEQ   1536
#define NB      2
#define MROWS   3072
#define DMODEL  512
#define NHEADS  8
#define DHEAD   64
#define DFF     2048
#define DMOTION 256
#define NLAYERS 6
#define PERIODN 15
#define CTXF    10
#define THRW    128
#define KIN     384           // 262 zero-padded to multiple of 128

__device__ __forceinline__ float bf2f(ushort_t u) { return __uint_as_float((uint_t)u << 16); }
__device__ __forceinline__ ushort_t f2bf(float f) {
    uint_t x = __float_as_uint(f);
    return (ushort_t)((x + 0x7fffu + ((x >> 16) & 1u)) >> 16);   // RNE
}

__device__ __forceinline__ void gl2lds(const ushort_t* g, ushort_t* l) {
    __builtin_amdgcn_global_load_lds((const __attribute__((address_space(1))) void*)g,
                                     (__attribute__((address_space(3))) void*)l, 16, 0, 0);
}

// ---------------------------------------------------------------------------
__global__ __launch_bounds__(256) void pe_k(float* __restrict__ pe) {
    int idx = blockIdx.x * 256 + threadIdx.x;
    if (idx >= PERIODN * DMODEL) return;
    int p = idx / DMODEL, c = idx % DMODEL;
    int j = (c < DMODEL / 2) ? c : (c - DMODEL / 2);
    float div = __expf(-logf(10000.0f) * (2.0f * (float)j) / (float)DMODEL);
    float ang = (float)p * div;
    pe[idx] = (c < DMODEL / 2) ? sinf(ang) : cosf(ang);
}

// ---------------------------------------------------------------------------
__global__ __launch_bounds__(256) void build_k(const float* __restrict__ motion,
                                               const float* __restrict__ traj,
                                               ushort_t* __restrict__ hin,
                                               float* __restrict__ mask_out) {
    int idx = blockIdx.x * 256 + threadIdx.x;
    if (idx >= MROWS * KIN) return;
    int row = idx / KIN, c = idx % KIN;
    int t = row % T_SEQ;
    float mv = (t < CTXF || t == T_SEQ - 1) ? 1.0f : 0.0f;
    float val;
    if (c < DMOTION)            val = motion[(size_t)row * DMOTION + c] * mv;
    else if (c < DMOTION + 5)   val = traj[(size_t)row * 5 + (c - DMOTION)];
    else if (c == DMOTION + 5)  val = mv;
    else                        val = 0.0f;
    hin[idx] = f2bf(val);
    if (c == 0) mask_out[row] = mv;
}

// ---------------------------------------------------------------------------
// ALL weight transpose-conversions in ONE dispatch (flat 32x32-tile decode).
// ---------------------------------------------------------------------------
__global__ __launch_bounds__(256)
void tconv_all_k(const float* __restrict__ wq, const float* __restrict__ wk,
                 const float* __restrict__ wv, const float* __restrict__ wo,
                 const float* __restrict__ fw1, const float* __restrict__ fw2,
                 const float* __restrict__ mw1, const float* __restrict__ mw2,
                 const float* __restrict__ dw1, const float* __restrict__ dw2,
                 ushort_t* __restrict__ qkvt, ushort_t* __restrict__ wot,
                 ushort_t* __restrict__ ffn1t, ushort_t* __restrict__ ffn2t,
                 ushort_t* __restrict__ mew1t, ushort_t* __restrict__ mew2t,
                 ushort_t* __restrict__ dec1t, ushort_t* __restrict__ dec2t) {
    __shared__ float t[32][33];
    int bid = blockIdx.x;
    const float* src; ushort_t* dst;
    int K, N, Kpad, kb, nb;
    if (bid < 4608) {                          // qkv: 18 z x 16x16
        int z = bid >> 8, r = bid & 255;
        int s = z % 3, l = z / 3;
        src = (s == 0 ? wq : s == 1 ? wk : wv) + (size_t)l * 262144;
        dst = qkvt + (size_t)z * 262144;
        K = 512; N = 512; Kpad = 512; kb = (r >> 4) * 32; nb = (r & 15) * 32;
    } else if (bid < 6144) {                   // wo: 6 z x 16x16
        int b2 = bid - 4608; int z = b2 >> 8, r = b2 & 255;
        src = wo + (size_t)z * 262144; dst = wot + (size_t)z * 262144;
        K = 512; N = 512; Kpad = 512; kb = (r >> 4) * 32; nb = (r & 15) * 32;
    } else if (bid < 12288) {                  // ffn1: 6 z x (16 kb x 64 nb)
        int b2 = bid - 6144; int z = b2 >> 10, r = b2 & 1023;
        src = fw1 + (size_t)z * 1048576; dst = ffn1t + (size_t)z * 1048576;
        K = 512; N = 2048; Kpad = 512; kb = (r >> 6) * 32; nb = (r & 63) * 32;
    } else if (bid < 18432) {                  // ffn2: 6 z x (64 kb x 16 nb)
        int b2 = bid - 12288; int z = b2 >> 10, r = b2 & 1023;
        src = fw2 + (size_t)z * 1048576; dst = ffn2t + (size_t)z * 1048576;
        K = 2048; N = 512; Kpad = 2048; kb = (r >> 4) * 32; nb = (r & 15) * 32;
    } else if (bid < 18624) {                  // mew1: 12 kb x 16 nb
        int r = bid - 18432;
        src = mw1; dst = mew1t;
        K = 262; N = 512; Kpad = KIN; kb = (r >> 4) * 32; nb = (r & 15) * 32;
    } else if (bid < 18880) {                  // mew2: 16x16
        int r = bid - 18624;
        src = mw2; dst = mew2t;
        K = 512; N = 512; Kpad = 512; kb = (r >> 4) * 32; nb = (r & 15) * 32;
    } else if (bid < 19136) {                  // dec1: 16x16
        int r = bid - 18880;
        src = dw1; dst = dec1t;
        K = 512; N = 512; Kpad = 512; kb = (r >> 4) * 32; nb = (r & 15) * 32;
    } else {                                   // dec2: 16 kb x 8 nb
        int r = bid - 19136;
        src = dw2; dst = dec2t;
        K = 512; N = 256; Kpad = 512; kb = (r >> 3) * 32; nb = (r & 7) * 32;
    }
    const int tx = threadIdx.x & 31, ty = threadIdx.x >> 5;
#pragma unroll
    for (int i = 0; i < 4; ++i) {
        int k = kb + ty + i * 8, n = nb + tx;
        t[ty + i * 8][tx] = (k < K && n < N) ? src[(size_t)k * N + n] : 0.0f;
    }
    __syncthreads();
#pragma unroll
    for (int i = 0; i < 4; ++i) {
        int n = nb + ty + i * 8, kk = kb + tx;
        if (n < N && kk < Kpad) dst[(size_t)n * Kpad + kk] = f2bf(t[tx][ty + i * 8]);
    }
}

__global__ __launch_bounds__(256)
void bcat_k(const float* __restrict__ bq, const float* __restrict__ bk,
            const float* __restrict__ bv, float* __restrict__ bqkv) {
    int idx = blockIdx.x * 256 + threadIdx.x;
    if (idx >= NLAYERS * 3 * DMODEL) return;
    int l = idx / (3 * DMODEL), n = idx % (3 * DMODEL);
    int s = n >> 9, c = n & 511;
    const float* b = (s == 0 ? bq : s == 1 ? bk : bv);
    bqkv[idx] = b[l * DMODEL + c];
}

// ---------------------------------------------------------------------------
// Full-M split-K bf16 MFMA GEMM (round-9 proven). ACT: 0 none, 1 leaky,
// 2 relu, 3 final-blend (v = res*mv + v*(1-mv)).
// ---------------------------------------------------------------------------
#define CL  68
template <int ACT, bool RES, bool PE, bool OUTBF>
__global__ __launch_bounds__(256)
void qgemm_k(const ushort_t* __restrict__ A, int K,
             const ushort_t* __restrict__ Wt,
             const float* __restrict__ bias,
             const float* __restrict__ res,
             const float* __restrict__ pe15,
             void* __restrict__ Cout, int N) {
    __shared__ ushort_t smem[2][(32 + 64) * 128];
    const int tid = threadIdx.x;
    const int lane = tid & 63, wid = tid >> 6;
    const int m0 = blockIdx.y * 32, n0 = blockIdx.x * 64;
    const int l4 = lane >> 4, l15 = lane & 15;
    const int lrow = lane >> 4;
    const int lu   = lane & 15;

    f32x4 acc[2][4];
#pragma unroll
    for (int m = 0; m < 2; ++m)
#pragma unroll
        for (int n = 0; n < 4; ++n) acc[m][n] = (f32x4){0.f, 0.f, 0.f, 0.f};

    const int niter = K >> 7;

    auto stage = [&](int buf, int k0) {
        ushort_t* dst = &smem[buf][0];
#pragma unroll
        for (int j = 0; j < 6; ++j) {
            const int inst = wid * 6 + j;
            if (inst < 8) {
                const int row = inst * 4 + lrow;
                const int u = lu ^ (row & 15);
                gl2lds(A + (size_t)(m0 + row) * K + k0 + u * 8, dst + inst * 512);
            } else {
                const int bi = inst - 8;
                const int row = bi * 4 + lrow;
                const int u = lu ^ (row & 15);
                gl2lds(Wt + (size_t)(n0 + row) * K + k0 + u * 8,
                       dst + 32 * 128 + bi * 512);
            }
        }
    };

    const int kbyte = wid * 64;
    auto rdfrag = [&](const ushort_t* t, int row) -> bf16x8 {
        const int off0 = kbyte + l4 * 8;
        const int off1 = kbyte + 32 + l4 * 8;
        const int a0 = row * 256 + (((off0 & ~15) ^ ((row & 15) << 4)) | (off0 & 15));
        const int a1 = row * 256 + (((off1 & ~15) ^ ((row & 15) << 4)) | (off1 & 15));
        bf16x4 lo = *(const bf16x4*)((const char*)t + a0);
        bf16x4 hi = *(const bf16x4*)((const char*)t + a1);
        return __builtin_shufflevector(lo, hi, 0, 1, 2, 3, 4, 5, 6, 7);
    };

    stage(0, 0);
    __syncthreads();
    int cur = 0;
    for (int t = 0; t < niter; ++t) {
        if (t + 1 < niter) stage(cur ^ 1, (t + 1) << 7);
        const ushort_t* As = &smem[cur][0];
        const ushort_t* Bs = &smem[cur][32 * 128];
        bf16x8 af[2], bf[4];
#pragma unroll
        for (int m = 0; m < 2; ++m) af[m] = rdfrag(As, m * 16 + l15);
#pragma unroll
        for (int n = 0; n < 4; ++n) bf[n] = rdfrag(Bs, n * 16 + l15);
#pragma unroll
        for (int m = 0; m < 2; ++m)
#pragma unroll
            for (int n = 0; n < 4; ++n)
                acc[m][n] = __builtin_amdgcn_mfma_f32_16x16x32_bf16(af[m], bf[n], acc[m][n], 0, 0, 0);
        __syncthreads();
        cur ^= 1;
    }

    float* cb0 = (float*)&smem[0][0];
    float* cb1 = (float*)&smem[1][0];
    if (wid >= 2) {
        float* cb = (wid == 2) ? cb0 : cb1;
#pragma unroll
        for (int m = 0; m < 2; ++m)
#pragma unroll
            for (int n = 0; n < 4; ++n)
#pragma unroll
                for (int r = 0; r < 4; ++r)
                    cb[(m * 16 + l4 * 4 + r) * CL + n * 16 + l15] = acc[m][n][r];
    }
    __syncthreads();
    if (wid < 2) {
        float* cb = (wid == 0) ? cb0 : cb1;
#pragma unroll
        for (int m = 0; m < 2; ++m)
#pragma unroll
            for (int n = 0; n < 4; ++n)
#pragma unroll
                for (int r = 0; r < 4; ++r)
                    cb[(m * 16 + l4 * 4 + r) * CL + n * 16 + l15] += acc[m][n][r];
    }
    __syncthreads();

    const int row = tid >> 3, c0 = (tid & 7) * 8;
    const int grow = m0 + row;
#pragma unroll
    for (int j = 0; j < 8; ++j) {
        const int gcol = n0 + c0 + j;
        float v = cb0[row * CL + c0 + j] + cb1[row * CL + c0 + j] + bias[gcol];
        if (ACT == 1) v = v >= 0.f ? v : 0.01f * v;
        else if (ACT == 2) v = fmaxf(v, 0.f);
        else if (ACT == 3) {
            const int t2 = grow % T_SEQ;
            const float mv = (t2 < CTXF || t2 == T_SEQ - 1) ? 1.0f : 0.0f;
            v = res[(size_t)grow * N + gcol] * mv + v * (1.0f - mv);
        }
        if (PE) v += pe15[((grow % T_SEQ) % PERIODN) * DMODEL + gcol];
        if (RES) v += res[(size_t)grow * N + gcol];
        if (OUTBF) ((ushort_t*)Cout)[(size_t)grow * N + gcol] = f2bf(v);
        else       ((float*)Cout)[(size_t)grow * N + gcol] = v;
    }
}

// ---------------------------------------------------------------------------
// Packed-row GEMM over two row-intervals per batch (K = 512, lda = 512).
// Used for the out-projection (active query rows only, f32 residual out).
// ---------------------------------------------------------------------------
template <bool RES, bool OUTBF>
__global__ __launch_bounds__(256)
void pgemm_k(const ushort_t* __restrict__ A,
             const ushort_t* __restrict__ Wt,
             const float* __restrict__ bias,
             const float* __restrict__ res,
             void* __restrict__ Cout, int ldc,
             int tpb, int len1, int start2, int nact) {
    __shared__ ushort_t smem[2][(32 + 64) * 128];
    const int tid = threadIdx.x;
    const int lane = tid & 63, wid = tid >> 6;
    const int ty = blockIdx.y;
    const int bb = (ty >= tpb) ? 1 : 0;
    const int t32 = (ty - bb * tpb) * 32;
    const int n0 = blockIdx.x * 64;
    const int l4 = lane >> 4, l15 = lane & 15;
    const int lrow = lane >> 4;
    const int lu   = lane & 15;

    auto maprow = [&](int pr) -> size_t {
        int r = t32 + pr;
        r = min(r, nact - 1);
        int tt = (r < len1) ? r : (start2 + (r - len1));
        return (size_t)(bb * T_SEQ + tt);
    };

    f32x4 acc[2][4];
#pragma unroll
    for (int m = 0; m < 2; ++m)
#pragma unroll
        for (int n = 0; n < 4; ++n) acc[m][n] = (f32x4){0.f, 0.f, 0.f, 0.f};

    auto stage = [&](int buf, int k0) {
        ushort_t* dst = &smem[buf][0];
#pragma unroll
        for (int j = 0; j < 6; ++j) {
            const int inst = wid * 6 + j;
            if (inst < 8) {
                const int row = inst * 4 + lrow;
                const int u = lu ^ (row & 15);
                gl2lds(A + maprow(row) * 512 + k0 + u * 8, dst + inst * 512);
            } else {
                const int bi = inst - 8;
                const int row = bi * 4 + lrow;
                const int u = lu ^ (row & 15);
                gl2lds(Wt + (size_t)(n0 + row) * 512 + k0 + u * 8,
                       dst + 32 * 128 + bi * 512);
            }
        }
    };

    const int kbyte = wid * 64;
    auto rdfrag = [&](const ushort_t* t, int row) -> bf16x8 {
        const int off0 = kbyte + l4 * 8;
        const int off1 = kbyte + 32 + l4 * 8;
        const int a0 = row * 256 + (((off0 & ~15) ^ ((row & 15) << 4)) | (off0 & 15));
        const int a1 = row * 256 + (((off1 & ~15) ^ ((row & 15) << 4)) | (off1 & 15));
        bf16x4 lo = *(const bf16x4*)((const char*)t + a0);
        bf16x4 hi = *(const bf16x4*)((const char*)t + a1);
        return __builtin_shufflevector(lo, hi, 0, 1, 2, 3, 4, 5, 6, 7);
    };

    stage(0, 0);
    __syncthreads();
    int cur = 0;
    for (int t = 0; t < 4; ++t) {
        if (t + 1 < 4) stage(cur ^ 1, (t + 1) << 7);
        const ushort_t* As = &smem[cur][0];
        const ushort_t* Bs = &smem[cur][32 * 128];
        bf16x8 af[2], bf[4];
#pragma unroll
        for (int m = 0; m < 2; ++m) af[m] = rdfrag(As, m * 16 + l15);
#pragma unroll
        for (int n = 0; n < 4; ++n) bf[n] = rdfrag(Bs, n * 16 + l15);
#pragma unroll
        for (int m = 0; m < 2; ++m)
#pragma unroll
            for (int n = 0; n < 4; ++n)
                acc[m][n] = __builtin_amdgcn_mfma_f32_16x16x32_bf16(af[m], bf[n], acc[m][n], 0, 0, 0);
        __syncthreads();
        cur ^= 1;
    }

    float* cb0 = (float*)&smem[0][0];
    float* cb1 = (float*)&smem[1][0];
    if (wid >= 2) {
        float* cb = (wid == 2) ? cb0 : cb1;
#pragma unroll
        for (int m = 0; m < 2; ++m)
#pragma unroll
            for (int n = 0; n < 4; ++n)
#pragma unroll
                for (int r = 0; r < 4; ++r)
                    cb[(m * 16 + l4 * 4 + r) * CL + n * 16 + l15] = acc[m][n][r];
    }
    __syncthreads();
    if (wid < 2) {
        float* cb = (wid == 0) ? cb0 : cb1;
#pragma unroll
        for (int m = 0; m < 2; ++m)
#pragma unroll
            for (int n = 0; n < 4; ++n)
#pragma unroll
                for (int r = 0; r < 4; ++r)
                    cb[(m * 16 + l4 * 4 + r) * CL + n * 16 + l15] += acc[m][n][r];
    }
    __syncthreads();

    const int row = tid >> 3, c0 = (tid & 7) * 8;
    const int pr = t32 + row;
    if (pr >= nact) return;
    const int tt = (pr < len1) ? pr : (start2 + (pr - len1));
    const size_t grow = (size_t)(bb * T_SEQ + tt);
#pragma unroll
    for (int j = 0; j < 8; ++j) {
        const int gcol = n0 + c0 + j;
        float v = cb0[row * CL + c0 + j] + cb1[row * CL + c0 + j] + bias[gcol];
        if (RES) v += res[grow * ldc + gcol];
        if (OUTBF) ((ushort_t*)Cout)[grow * ldc + gcol] = f2bf(v);
        else       ((float*)Cout)[grow * ldc + gcol] = v;
    }
}

// ---------------------------------------------------------------------------
// Merged packed Q + KV GEMM in ONE dispatch. Block decodes part from
// blockIdx.y: [0, 2*tpbQ) -> Q (8 n-tiles, cols 0..511, active query rows);
// rest -> KV (16 n-tiles, cols 512..1535, allowed key rows). ldc = 1536.
// ---------------------------------------------------------------------------
__global__ __launch_bounds__(256)
void qkv_k(const ushort_t* __restrict__ A,
           const ushort_t* __restrict__ qw, const ushort_t* __restrict__ kvw,
           const float* __restrict__ biasq, ushort_t* __restrict__ Cout,
           int tpbQ, int len1Q, int start2Q, int nactQ,
           int tpbK, int len1K, int start2K, int nactK) {
    __shared__ ushort_t smem[2][(32 + 64) * 128];
    const int tid = threadIdx.x;
    const int lane = tid & 63, wid = tid >> 6;
    int tyl, tpb, len1, start2, nact, outoff;
    const ushort_t* W;
    if ((int)blockIdx.y < 2 * tpbQ) {
        if (blockIdx.x >= 8) return;
        tyl = blockIdx.y; tpb = tpbQ; len1 = len1Q; start2 = start2Q; nact = nactQ;
        outoff = 0; W = qw;
    } else {
        tyl = blockIdx.y - 2 * tpbQ; tpb = tpbK; len1 = len1K; start2 = start2K; nact = nactK;
        outoff = 512; W = kvw;
    }
    const int bb = (tyl >= tpb) ? 1 : 0;
    const int t32 = (tyl - bb * tpb) * 32;
    const int n0 = blockIdx.x * 64;
    const int l4 = lane >> 4, l15 = lane & 15;
    const int lrow = lane >> 4;
    const int lu   = lane & 15;

    auto maprow = [&](int pr) -> size_t {
        int r = t32 + pr;
        r = min(r, nact - 1);
        int tt = (r < len1) ? r : (start2 + (r - len1));
        return (size_t)(bb * T_SEQ + tt);
    };

    f32x4 acc[2][4];
#pragma unroll
    for (int m = 0; m < 2; ++m)
#pragma unroll
        for (int n = 0; n < 4; ++n) acc[m][n] = (f32x4){0.f, 0.f, 0.f, 0.f};

    auto stage = [&](int buf, int k0) {
        ushort_t* dst = &smem[buf][0];
#pragma unroll
        for (int j = 0; j < 6; ++j) {
            const int inst = wid * 6 + j;
            if (inst < 8) {
                const int row = inst * 4 + lrow;
                const int u = lu ^ (row & 15);
                gl2lds(A + maprow(row) * 512 + k0 + u * 8, dst + inst * 512);
            } else {
                const int bi = inst - 8;
                const int row = bi * 4 + lrow;
                const int u = lu ^ (row & 15);
                gl2lds(W + (size_t)(n0 + row) * 512 + k0 + u * 8,
                       dst + 32 * 128 + bi * 512);
            }
        }
    };

    const int kbyte = wid * 64;
    auto rdfrag = [&](const ushort_t* t, int row) -> bf16x8 {
        const int off0 = kbyte + l4 * 8;
        const int off1 = kbyte + 32 + l4 * 8;
        const int a0 = row * 256 + (((off0 & ~15) ^ ((row & 15) << 4)) | (off0 & 15));
        const int a1 = row * 256 + (((off1 & ~15) ^ ((row & 15) << 4)) | (off1 & 15));
        bf16x4 lo = *(const bf16x4*)((const char*)t + a0);
        bf16x4 hi = *(const bf16x4*)((const char*)t + a1);
        return __builtin_shufflevector(lo, hi, 0, 1, 2, 3, 4, 5, 6, 7);
    };

    stage(0, 0);
    __syncthreads();
    int cur = 0;
    for (int t = 0; t < 4; ++t) {
        if (t + 1 < 4) stage(cur ^ 1, (t + 1) << 7);
        const ushort_t* As = &smem[cur][0];
        const ushort_t* Bs = &smem[cur][32 * 128];
        bf16x8 af[2], bf[4];
#pragma unroll
        for (int m = 0; m < 2; ++m) af[m] = rdfrag(As, m * 16 + l15);
#pragma unroll
        for (int n = 0; n < 4; ++n) bf[n] = rdfrag(Bs, n * 16 + l15);
#pragma unroll
        for (int m = 0; m < 2; ++m)
#pragma unroll
            for (int n = 0; n < 4; ++n)
                acc[m][n] = __builtin_amdgcn_mfma_f32_16x16x32_bf16(af[m], bf[n], acc[m][n], 0, 0, 0);
        __syncthreads();
        cur ^= 1;
    }

    float* cb0 = (float*)&smem[0][0];
    float* cb1 = (float*)&smem[1][0];
    if (wid >= 2) {
        float* cb = (wid == 2) ? cb0 : cb1;
#pragma unroll
        for (int m = 0; m < 2; ++m)
#pragma unroll
            for (int n = 0; n < 4; ++n)
#pragma unroll
                for (int r = 0; r < 4; ++r)
                    cb[(m * 16 + l4 * 4 + r) * CL + n * 16 + l15] = acc[m][n][r];
    }
    __syncthreads();
    if (wid < 2) {
        float* cb = (wid == 0) ? cb0 : cb1;
#pragma unroll
        for (int m = 0; m < 2; ++m)
#pragma unroll
            for (int n = 0; n < 4; ++n)
#pragma unroll
                for (int r = 0; r < 4; ++r)
                    cb[(m * 16 + l4 * 4 + r) * CL + n * 16 + l15] += acc[m][n][r];
    }
    __syncthreads();

    const int row = tid >> 3, c0 = (tid & 7) * 8;
    const int pr = t32 + row;
    if (pr >= nact) return;
    const int tt = (pr < len1) ? pr : (start2 + (pr - len1));
    const size_t grow = (size_t)(bb * T_SEQ + tt);
#pragma unroll
    for (int j = 0; j < 8; ++j) {
        const int gcol = outoff + n0 + c0 + j;
        float v = cb0[row * CL + c0 + j] + cb1[row * CL + c0 + j] + biasq[gcol];
        Cout[grow * 1536 + gcol] = f2bf(v);
    }
}

// ---------------------------------------------------------------------------
// LayerNorm: f32 in, bf16 out. One wave per row.
// ---------------------------------------------------------------------------
__global__ __launch_bounds__(256)
void ln_k(const float* __restrict__ X, const float* __restrict__ g,
          const float* __restrict__ b, ushort_t* __restrict__ Y) {
    const int wid = threadIdx.x >> 6, lane = threadIdx.x & 63;
    const int row = blockIdx.x * 4 + wid;
    const float* x = X + (size_t)row * DMODEL;
    float v[8], s = 0.f;
#pragma unroll
    for (int j = 0; j < 8; ++j) { v[j] = x[lane + 64 * j]; s += v[j]; }
#pragma unroll
    for (int o = 32; o; o >>= 1) s += __shfl_xor(s, o);
    const float mean = s * (1.0f / DMODEL);
    float vs = 0.f;
#pragma unroll
    for (int j = 0; j < 8; ++j) { float d = v[j] - mean; vs += d * d; }
#pragma unroll
    for (int o = 32; o; o >>= 1) vs += __shfl_xor(vs, o);
    const float inv = rsqrtf(vs * (1.0f / DMODEL) + 1e-5f);
    ushort_t* y = Y + (size_t)row * DMODEL;
#pragma unroll
    for (int j = 0; j < 8; ++j) {
        const int c = lane + 64 * j;
        y[c] = f2bf((v[j] - mean) * inv * g[c] + b[c]);
    }
}

// ---------------------------------------------------------------------------
// LN2 with folded inactive-row x += vmo (writes x back, then normalizes).
// Rows with iLo <= t < iHi are inactive. iLo==iHi -> plain LN.
// ---------------------------------------------------------------------------
__global__ __launch_bounds__(256)
void ln2x_k(float* __restrict__ X, const float* __restrict__ vmo,
            const float* __restrict__ g, const float* __restrict__ b,
            ushort_t* __restrict__ Y, int iLo, int iHi) {
    const int wid = threadIdx.x >> 6, lane = threadIdx.x & 63;
    const int row = blockIdx.x * 4 + wid;
    const int t = row % T_SEQ, bb = row / T_SEQ;
    const bool inact = (t >= iLo) && (t < iHi);
    float* x = X + (size_t)row * DMODEL;
    float v[8], s = 0.f;
#pragma unroll
    for (int j = 0; j < 8; ++j) {
        const int c = lane + 64 * j;
        v[j] = x[c] + (inact ? vmo[bb * 512 + c] : 0.f);
        s += v[j];
    }
    if (inact) {
#pragma unroll
        for (int j = 0; j < 8; ++j) x[lane + 64 * j] = v[j];
    }
#pragma unroll
    for (int o = 32; o; o >>= 1) s += __shfl_xor(s, o);
    const float mean = s * (1.0f / DMODEL);
    float vs = 0.f;
#pragma unroll
    for (int j = 0; j < 8; ++j) { float d = v[j] - mean; vs += d * d; }
#pragma unroll
    for (int o = 32; o; o >>= 1) vs += __shfl_xor(vs, o);
    const float inv = rsqrtf(vs * (1.0f / DMODEL) + 1e-5f);
    ushort_t* y = Y + (size_t)row * DMODEL;
#pragma unroll
    for (int j = 0; j < 8; ++j) {
        const int c = lane + 64 * j;
        y[c] = f2bf((v[j] - mean) * inv * g[c] + b[c]);
    }
}

// ---------------------------------------------------------------------------
// V-mean partial row-sums of h. grid (NB, 8), 1024 thr.
// ---------------------------------------------------------------------------
__global__ __launch_bounds__(1024)
void vsum_k(const ushort_t* __restrict__ h, float* __restrict__ hp) {
    __shared__ float red[16][512];
    const int b = blockIdx.x, ch = blockIdx.y;
    const int rg = threadIdx.x >> 6;
    const int c8 = (threadIdx.x & 63) * 8;
    const ushort_t* hb = h + (size_t)(b * T_SEQ + ch * 192) * DMODEL + c8;
    float a[8] = {};
    for (int r = rg; r < 192; r += 16) {
        bf16x8 v = *(const bf16x8*)(hb + (size_t)r * DMODEL);
#pragma unroll
        for (int j = 0; j < 8; ++j) a[j] += (float)v[j];
    }
#pragma unroll
    for (int j = 0; j < 8; ++j) red[rg][c8 + j] = a[j];
    __syncthreads();
    if (threadIdx.x < 512) {
        float s = 0.f;
#pragma unroll
        for (int gi = 0; gi < 16; ++gi) s += red[gi][threadIdx.x];
        hp[(b * 8 + ch) * 512 + threadIdx.x] = s;
    }
}

// ---------------------------------------------------------------------------
// Merged vdot + gemv: vm = mean(h)@Wv + bv (LDS only), vmo = vm@WoT + bo.
// grid (NB), 512 threads.
// ---------------------------------------------------------------------------
__global__ __launch_bounds__(512)
void vmg_k(const float* __restrict__ hp, const ushort_t* __restrict__ wvt,
           const float* __restrict__ bv, const ushort_t* __restrict__ wot_l,
           const float* __restrict__ bo_l, float* __restrict__ vmo) {
    __shared__ float mh[512];
    __shared__ float vmld[512];
    const int b = blockIdx.x, t = threadIdx.x;
    float s = 0.f;
#pragma unroll
    for (int ch = 0; ch < 8; ++ch) s += hp[(b * 8 + ch) * 512 + t];
    mh[t] = s * (1.0f / T_SEQ);
    __syncthreads();
    const ushort_t* w = wvt + (size_t)t * 512;
    float acc = 0.f;
    for (int k = 0; k < 512; k += 8) {
        bf16x8 w8 = *(const bf16x8*)(w + k);
#pragma unroll
        for (int j = 0; j < 8; ++j) acc += mh[k + j] * (float)w8[j];
    }
    vmld[t] = acc + bv[t];
    __syncthreads();
    const ushort_t* w2 = wot_l + (size_t)t * 512;
    acc = 0.f;
    for (int k = 0; k < 512; k += 8) {
        bf16x8 w8 = *(const bf16x8*)(w2 + k);
#pragma unroll
        for (int j = 0; j < 8; ++j) acc += vmld[k + j] * (float)w8[j];
    }
    vmo[b * 512 + t] = acc + bo_l[t];
}

// ---------------------------------------------------------------------------
// MFMA flash attention (round-9 proven). One WAVE per 16-row q-subtile.
// ---------------------------------------------------------------------------
#define KLD 72
#define VLD 36
__global__ __launch_bounds__(256)
void attn3_k(const ushort_t* __restrict__ qkv, ushort_t* __restrict__ attout,
             int lo, int hi, int nlow, int qhi0, int tl, int st) {
    __shared__ ushort_t klds_[4][32 * KLD];
    __shared__ ushort_t vlds_[4][64 * VLD];
    const int lane = threadIdx.x & 63, wid = threadIdx.x >> 6;
    const int s = blockIdx.x * 4 + wid;
    if (s >= st) return;
    const int h = blockIdx.y, b = blockIdx.z;
    const int l15 = lane & 15, l4 = lane >> 4;

    int qb, qend;
    if (s < tl) { qb = 16 * s;                qend = nlow - 1; }
    else        { qb = qhi0 + 16 * (s - tl);  qend = T_SEQ - 1; }
    const int nr = qend - qb;

    ushort_t* klds = klds_[wid];
    ushort_t* vlds = vlds_[wid];
    const size_t rbase = (size_t)(b * T_SEQ) * 1536;
    const int q = qb + l15;

    const int qrow_r = min(q, T_SEQ - 1);
    const ushort_t* qptr = qkv + rbase + (size_t)qrow_r * 1536 + h * 64;
    bf16x8 bq[2];
#pragma unroll
    for (int kh = 0; kh < 2; ++kh) {
        bf16x4 lo4 = *(const bf16x4*)(qptr + kh * 32 + l4 * 4);
        bf16x4 hi4 = *(const bf16x4*)(qptr + kh * 32 + 16 + l4 * 4);
        bq[kh] = __builtin_shufflevector(lo4, hi4, 0, 1, 2, 3, 4, 5, 6, 7);
    }

    const int band0 = max(0, qb - THRW);
    const int band1 = min(T_SEQ - 1, qb + 15 + THRW);
    const int i1s = band0, i1e = min(band1, lo - 1);
    const int i2s = max(band0, hi), i2e = band1;

    f32x4 O[4] = {{0.f,0.f,0.f,0.f},{0.f,0.f,0.f,0.f},{0.f,0.f,0.f,0.f},{0.f,0.f,0.f,0.f}};
    float m = -3.0e38f, lsum = 0.f;

#pragma unroll 1
    for (int seg = 0; seg < 2; ++seg) {
        const int s0 = seg ? i2s : i1s, s1 = seg ? i2e : i1e;
#pragma unroll 1
        for (int c0 = s0; c0 <= s1; c0 += 32) {
#pragma unroll
            for (int i = 0; i < 4; ++i) {
                const int idx = i * 64 + lane;
                const int row = idx >> 3, c = (idx & 7) * 8;
                const int kr = min(c0 + row, T_SEQ - 1);
                const uint4 kv = *(const uint4*)(qkv + rbase + (size_t)kr * 1536 + 512 + h * 64 + c);
                *(uint4*)&klds[row * KLD + c] = kv;
                const uint4 vv = *(const uint4*)(qkv + rbase + (size_t)kr * 1536 + 1024 + h * 64 + c);
                const ushort_t* vp = (const ushort_t*)&vv;
#pragma unroll
                for (int d = 0; d < 8; ++d) vlds[(c + d) * VLD + row] = vp[d];
            }
            f32x4 sacc[2];
#pragma unroll
            for (int ks = 0; ks < 2; ++ks) {
                f32x4 a = {0.f, 0.f, 0.f, 0.f};
#pragma unroll
                for (int kh = 0; kh < 2; ++kh) {
                    const ushort_t* kp = &klds[(16 * ks + l15) * KLD + kh * 32];
                    bf16x4 lo4 = *(const bf16x4*)(kp + l4 * 4);
                    bf16x4 hi4 = *(const bf16x4*)(kp + 16 + l4 * 4);
                    bf16x8 ak = __builtin_shufflevector(lo4, hi4, 0, 1, 2, 3, 4, 5, 6, 7);
                    a = __builtin_amdgcn_mfma_f32_16x16x32_bf16(ak, bq[kh], a, 0, 0, 0);
                }
                sacc[ks] = a;
            }
            float sv[8];
            bool vld[8];
            float cm = -3.0e38f;
#pragma unroll
            for (int ks = 0; ks < 2; ++ks)
#pragma unroll
                for (int r = 0; r < 4; ++r) {
                    const int key = c0 + 16 * ks + 4 * l4 + r;
                    const int dist = (q > key) ? (q - key) : (key - q);
                    const bool v = (dist <= THRW) && (key < lo || key >= hi) && (key < T_SEQ);
                    const int ii = ks * 4 + r;
                    sv[ii] = sacc[ks][r] * 0.125f - (float)(dist / PERIODN);
                    vld[ii] = v;
                    cm = fmaxf(cm, v ? sv[ii] : -3.0e38f);
                }
            cm = fmaxf(cm, __shfl_xor(cm, 16));
            cm = fmaxf(cm, __shfl_xor(cm, 32));
            const float mnew = fmaxf(m, cm);
            const float sc = __expf(m - mnew);
            m = mnew;
            float p[8], psum = 0.f;
#pragma unroll
            for (int ii = 0; ii < 8; ++ii) {
                p[ii] = vld[ii] ? __expf(sv[ii] - mnew) : 0.f;
                psum += p[ii];
            }
            psum += __shfl_xor(psum, 16);
            psum += __shfl_xor(psum, 32);
            lsum = lsum * sc + psum;
#pragma unroll
            for (int ds = 0; ds < 4; ++ds) O[ds] *= sc;
            bf16x8 pb;
#pragma unroll
            for (int ii = 0; ii < 8; ++ii) pb[ii] = (__bf16)p[ii];
#pragma unroll
            for (int ds = 0; ds < 4; ++ds) {
                const ushort_t* vp2 = &vlds[(16 * ds + l15) * VLD];
                bf16x4 lo4 = *(const bf16x4*)(vp2 + 4 * l4);
                bf16x4 hi4 = *(const bf16x4*)(vp2 + 16 + 4 * l4);
                bf16x8 av = __builtin_shufflevector(lo4, hi4, 0, 1, 2, 3, 4, 5, 6, 7);
                O[ds] = __builtin_amdgcn_mfma_f32_16x16x32_bf16(av, pb, O[ds], 0, 0, 0);
            }
        }
    }
    if (l15 <= nr) {
        const float inv = 1.0f / lsum;
        ushort_t* op = attout + (size_t)(b * T_SEQ + qb + l15) * DMODEL + h * 64;
#pragma unroll
        for (int ds = 0; ds < 4; ++ds)
#pragma unroll
            for (int r = 0; r < 4; ++r)
                op[16 * ds + 4 * l4 + r] = f2bf(O[ds][r] * inv);
    }
}

// ---------------------------------------------------------------------------
extern "C" void kernel_launch(void* const* d_in, const int* in_sizes, int n_in,
                              void* d_out, int out_size, void* d_ws, size_t ws_size,
                              hipStream_t stream) {
    const float* motion = (const float*)d_in[0];
    const float* traj   = (const float*)d_in[1];
    const float* me_w1  = (const float*)d_in[2];
    const float* me_b1  = (const float*)d_in[3];
    const float* me_w2  = (const float*)d_in[4];
    const float* me_b2  = (const float*)d_in[5];
    const float* wq = (const float*)d_in[6];
    const float* bq = (const float*)d_in[7];
    const float* wk = (const float*)d_in[8];
    const float* bk = (const float*)d_in[9];
    const float* wv = (const float*)d_in[10];
    const float* bv = (const float*)d_in[11];
    const float* wo = (const float*)d_in[12];
    const float* bo = (const float*)d_in[13];
    const float* ln1_g = (const float*)d_in[14];
    const float* ln1_b = (const float*)d_in[15];
    const float* ffn_w1 = (const float*)d_in[16];
    const float* ffn_b1 = (const float*)d_in[17];
    const float* ffn_w2 = (const float*)d_in[18];
    const float* ffn_b2 = (const float*)d_in[19];
    const float* ln2_g = (const float*)d_in[20];
    const float* ln2_b = (const float*)d_in[21];
    const float* fln_g = (const float*)d_in[22];
    const float* fln_b = (const float*)d_in[23];
    const float* dec_w1 = (const float*)d_in[24];
    const float* dec_b1 = (const float*)d_in[25];
    const float* dec_w2 = (const float*)d_in[26];
    const float* dec_b2 = (const float*)d_in[27];

    float* out = (float*)d_out;
    float* mask_out = out + (size_t)MROWS * DMOTION;

    char* base = (char*)d_ws;
    auto alloc = [&](size_t bytes) { char* p = base; base += (bytes + 255) & ~(size_t)255; return p; };

    ushort_t* qkvt  = (ushort_t*)alloc((size_t)NLAYERS * 1536 * 512 * 2);
    ushort_t* wot   = (ushort_t*)alloc((size_t)NLAYERS * 512 * 512 * 2);
    ushort_t* ffn1t = (ushort_t*)alloc((size_t)NLAYERS * 2048 * 512 * 2);
    ushort_t* ffn2t = (ushort_t*)alloc((size_t)NLAYERS * 512 * 2048 * 2);
    ushort_t* mew1t = (ushort_t*)alloc((size_t)512 * KIN * 2);
    ushort_t* mew2t = (ushort_t*)alloc((size_t)512 * 512 * 2);
    ushort_t* dec1t = (ushort_t*)alloc((size_t)512 * 512 * 2);
    ushort_t* dec2t = (ushort_t*)alloc((size_t)256 * 512 * 2);
    float*    bqkv  = (float*)alloc((size_t)NLAYERS * 1536 * 4);
    float*    pe15  = (float*)alloc((size_t)PERIODN * DMODEL * 4);
    float*    hp    = (float*)alloc((size_t)NB * 8 * 512 * 4);
    float*    vmo   = (float*)alloc((size_t)NB * 512 * 4);
    ushort_t* hin   = (ushort_t*)alloc((size_t)MROWS * KIN * 2);
    float*    x     = (float*)alloc((size_t)MROWS * DMODEL * 4);
    ushort_t* h     = (ushort_t*)alloc((size_t)MROWS * DMODEL * 2);
    ushort_t* qkv   = (ushort_t*)alloc((size_t)MROWS * 1536 * 2);
    ushort_t* ff    = (ushort_t*)alloc((size_t)MROWS * DFF * 2);

    const dim3 blk(256);
    pe_k<<<(PERIODN * DMODEL + 255) / 256, blk, 0, stream>>>(pe15);
    build_k<<<(MROWS * KIN + 255) / 256, blk, 0, stream>>>(motion, traj, hin, mask_out);
    tconv_all_k<<<19264, blk, 0, stream>>>(wq, wk, wv, wo, ffn_w1, ffn_w2,
                                           me_w1, me_w2, dec_w1, dec_w2,
                                           qkvt, wot, ffn1t, ffn2t,
                                           mew1t, mew2t, dec1t, dec2t);
    bcat_k<<<(NLAYERS * 1536 + 255) / 256, blk, 0, stream>>>(bq, bk, bv, bqkv);

    const dim3 gs512(8, 96), gsff(32, 96), gs256(4, 96);

    // motion encoder
    qgemm_k<1, false, false, true ><<<gs512, blk, 0, stream>>>(hin, KIN, mew1t, me_b1, nullptr, nullptr, h, 512);
    qgemm_k<1, false, true,  false><<<gs512, blk, 0, stream>>>(h, 512, mew2t, me_b2, nullptr, pe15, x, 512);

    for (int i = 0; i < NLAYERS; ++i) {
        const int lo = CTXF + THRW * i;
        const int hi = (T_SEQ - 1) - THRW * i;
        int qlow_end = lo + 127;
        int qhi0 = hi - 128;
        int nlow, ninact;
        if (qhi0 <= qlow_end + 1) {
            nlow = T_SEQ; qhi0 = T_SEQ; ninact = 0;
        } else {
            nlow = qlow_end + 1;
            ninact = qhi0 - nlow;
        }
        const int tl2 = (nlow + 15) / 16;
        const int th2 = (T_SEQ - qhi0 + 15) / 16;
        const int st  = tl2 + th2;
        const int nact_q = nlow + (T_SEQ - qhi0);
        const int tpb_q  = (nact_q + 31) / 32;
        const int nkeys  = lo + (T_SEQ - hi);
        const int tpb_kv = (nkeys + 31) / 32;

        const ushort_t* qw  = qkvt + (size_t)i * 1536 * 512;
        const ushort_t* kvw = qw + (size_t)512 * 512;
        const ushort_t* vw  = qw + (size_t)1024 * 512;
        const float* bq_i   = bqkv + i * 1536;
        const ushort_t* wot_i = wot + (size_t)i * 512 * 512;

        ln_k<<<MROWS / 4, blk, 0, stream>>>(x, ln1_g + i * 512, ln1_b + i * 512, h);
        qkv_k<<<dim3(16, 2 * tpb_q + 2 * tpb_kv), blk, 0, stream>>>(
            h, qw, kvw, bq_i, qkv,
            tpb_q, nlow, qhi0, nact_q, tpb_kv, lo, hi, nkeys);
        if (ninact > 0) {
            vsum_k<<<dim3(NB, 8), dim3(1024), 0, stream>>>(h, hp);
            vmg_k<<<dim3(NB), dim3(512), 0, stream>>>(hp, vw, bq_i + 1024, wot_i, bo + i * 512, vmo);
        }
        attn3_k<<<dim3((st + 3) / 4, NHEADS, NB), blk, 0, stream>>>(qkv, h, lo, hi, nlow, qhi0, tl2, st);
        pgemm_k<true, false><<<dim3(8, 2 * tpb_q), blk, 0, stream>>>(
            h, wot_i, bo + i * 512, x, x, 512, tpb_q, nlow, qhi0, nact_q);
        ln2x_k<<<MROWS / 4, blk, 0, stream>>>(x, vmo, ln2_g + i * 512, ln2_b + i * 512, h,
                                              ninact > 0 ? nlow : 0, ninact > 0 ? qhi0 : 0);
        qgemm_k<2, false, false, true><<<gsff, blk, 0, stream>>>(h, 512, ffn1t + (size_t)i * 2048 * 512, ffn_b1 + i * 2048, nullptr, nullptr, ff, 2048);
        qgemm_k<0, true, false, false><<<gs512, blk, 0, stream>>>(ff, 2048, ffn2t + (size_t)i * 512 * 2048, ffn_b2 + i * 512, x, nullptr, x, 512);
    }

    // decoder: dec1 (leaky) -> dec2 fused with final blend (ACT=3, res=motion)
    ln_k<<<MROWS / 4, blk, 0, stream>>>(x, fln_g, fln_b, h);
    qgemm_k<1, false, false, true ><<<gs512, blk, 0, stream>>>(h, 512, dec1t, dec_b1, nullptr, nullptr, ff, 512);
    qgemm_k<3, false, false, false><<<gs256, blk, 0, stream>>>(ff, 512, dec2t, dec_b2, motion, nullptr, out, 256);
}

// Round 13
// 809.325 us; speedup vs baseline: 1.1025x; 1.1025x over previous
//
#include <hip/hip_runtime.h>
#include <math.h>

typedef unsigned short ushort_t;
typedef unsigned int uint_t;
typedef __bf16 bf16x4 __attribute__((ext_vector_type(4)));
typedef __bf16 bf16x8 __attribute__((ext_vector_type(8)));
typedef float f32x4 __attribute__((ext_vector_type(4)));

#define T_SEQ   1536
#define NB      2
#define MROWS   3072
#define DMODEL  512
#define NHEADS  8
#define DHEAD   64
#define DFF     2048
#define DMOTION 256
#define NLAYERS 6
#define PERIODN 15
#define CTXF    10
#define THRW    128
#define KIN     384           // 262 zero-padded to multiple of 128

__device__ __forceinline__ float bf2f(ushort_t u) { return __uint_as_float((uint_t)u << 16); }
__device__ __forceinline__ ushort_t f2bf(float f) {
    uint_t x = __float_as_uint(f);
    return (ushort_t)((x + 0x7fffu + ((x >> 16) & 1u)) >> 16);   // RNE
}

__device__ __forceinline__ void gl2lds(const ushort_t* g, ushort_t* l) {
    __builtin_amdgcn_global_load_lds((const __attribute__((address_space(1))) void*)g,
                                     (__attribute__((address_space(3))) void*)l, 16, 0, 0);
}

// ---------------------------------------------------------------------------
__global__ __launch_bounds__(256) void pe_k(float* __restrict__ pe) {
    int idx = blockIdx.x * 256 + threadIdx.x;
    if (idx >= PERIODN * DMODEL) return;
    int p = idx / DMODEL, c = idx % DMODEL;
    int j = (c < DMODEL / 2) ? c : (c - DMODEL / 2);
    float div = __expf(-logf(10000.0f) * (2.0f * (float)j) / (float)DMODEL);
    float ang = (float)p * div;
    pe[idx] = (c < DMODEL / 2) ? sinf(ang) : cosf(ang);
}

// ---------------------------------------------------------------------------
__global__ __launch_bounds__(256) void build_k(const float* __restrict__ motion,
                                               const float* __restrict__ traj,
                                               ushort_t* __restrict__ hin,
                                               float* __restrict__ mask_out) {
    int idx = blockIdx.x * 256 + threadIdx.x;
    if (idx >= MROWS * KIN) return;
    int row = idx / KIN, c = idx % KIN;
    int t = row % T_SEQ;
    float mv = (t < CTXF || t == T_SEQ - 1) ? 1.0f : 0.0f;
    float val;
    if (c < DMOTION)            val = motion[(size_t)row * DMOTION + c] * mv;
    else if (c < DMOTION + 5)   val = traj[(size_t)row * 5 + (c - DMOTION)];
    else if (c == DMOTION + 5)  val = mv;
    else                        val = 0.0f;
    hin[idx] = f2bf(val);
    if (c == 0) mask_out[row] = mv;
}

// ---------------------------------------------------------------------------
__global__ __launch_bounds__(256)
void tconv_k(const float* __restrict__ src, size_t sstride,
             ushort_t* __restrict__ dst, size_t dstride,
             int K, int N, int Kpad) {
    __shared__ float t[32][33];
    src += (size_t)blockIdx.z * sstride;
    dst += (size_t)blockIdx.z * dstride;
    const int kb = blockIdx.y * 32, nb = blockIdx.x * 32;
    const int tx = threadIdx.x & 31, ty = threadIdx.x >> 5;
#pragma unroll
    for (int i = 0; i < 4; ++i) {
        int k = kb + ty + i * 8, n = nb + tx;
        t[ty + i * 8][tx] = (k < K && n < N) ? src[(size_t)k * N + n] : 0.0f;
    }
    __syncthreads();
#pragma unroll
    for (int i = 0; i < 4; ++i) {
        int n = nb + ty + i * 8, kk = kb + tx;
        if (n < N && kk < Kpad) dst[(size_t)n * Kpad + kk] = f2bf(t[tx][ty + i * 8]);
    }
}

// QKV concat transpose: z = layer*3+seg; dst = qkvt[l][seg*512 + n][k]
__global__ __launch_bounds__(256)
void tconv_qkv_k(const float* __restrict__ wq, const float* __restrict__ wk,
                 const float* __restrict__ wv, ushort_t* __restrict__ qkvt) {
    __shared__ float t[32][33];
    const int z = blockIdx.z, s = z % 3, l = z / 3;
    const float* src = (s == 0 ? wq : s == 1 ? wk : wv) + (size_t)l * DMODEL * DMODEL;
    ushort_t* dst = qkvt + (size_t)z * DMODEL * DMODEL;
    const int kb = blockIdx.y * 32, nb = blockIdx.x * 32;
    const int tx = threadIdx.x & 31, ty = threadIdx.x >> 5;
#pragma unroll
    for (int i = 0; i < 4; ++i)
        t[ty + i * 8][tx] = src[(size_t)(kb + ty + i * 8) * DMODEL + nb + tx];
    __syncthreads();
#pragma unroll
    for (int i = 0; i < 4; ++i)
        dst[(size_t)(nb + ty + i * 8) * DMODEL + kb + tx] = f2bf(t[tx][ty + i * 8]);
}

__global__ __launch_bounds__(256)
void bcat_k(const float* __restrict__ bq, const float* __restrict__ bk,
            const float* __restrict__ bv, float* __restrict__ bqkv) {
    int idx = blockIdx.x * 256 + threadIdx.x;
    if (idx >= NLAYERS * 3 * DMODEL) return;
    int l = idx / (3 * DMODEL), n = idx % (3 * DMODEL);
    int s = n >> 9, c = n & 511;
    const float* b = (s == 0 ? bq : s == 1 ? bk : bv);
    bqkv[idx] = b[l * DMODEL + c];
}

// ---------------------------------------------------------------------------
// Pipelined split-K bf16 MFMA GEMM (round-9 proven): 32x64 tile, 4 waves
// each owning a 32-wide k-slice of BK=128. Double-buffered LINEAR LDS via
// global_load_lds (zero staging VGPRs); source-XOR swizzle for conflicts.
// ACT: 0 none, 1 leaky, 2 relu, 3 final-blend (v = res*mv + v*(1-mv)).
// ---------------------------------------------------------------------------
#define CL  68      // f32 reduce-buffer row stride
template <int ACT, bool RES, bool PE, bool OUTBF>
__global__ __launch_bounds__(256)
void qgemm_k(const ushort_t* __restrict__ A, int K,
             const ushort_t* __restrict__ Wt,
             const float* __restrict__ bias,
             const float* __restrict__ res,
             const float* __restrict__ pe15,
             void* __restrict__ Cout, int N) {
    __shared__ ushort_t smem[2][(32 + 64) * 128];   // 2 x 24 KB, A | B, linear
    const int tid = threadIdx.x;
    const int lane = tid & 63, wid = tid >> 6;
    const int m0 = blockIdx.y * 32, n0 = blockIdx.x * 64;
    const int l4 = lane >> 4, l15 = lane & 15;
    const int lrow = lane >> 4;          // row within a 4-row stage instruction
    const int lu   = lane & 15;          // swizzled 16B-unit index u'

    f32x4 acc[2][4];
#pragma unroll
    for (int m = 0; m < 2; ++m)
#pragma unroll
        for (int n = 0; n < 4; ++n) acc[m][n] = (f32x4){0.f, 0.f, 0.f, 0.f};

    const int niter = K >> 7;                       // K multiple of 128

    auto stage = [&](int buf, int k0) {
        ushort_t* dst = &smem[buf][0];
#pragma unroll
        for (int j = 0; j < 6; ++j) {
            const int inst = wid * 6 + j;
            if (inst < 8) {
                const int row = inst * 4 + lrow;            // A row 0..31
                const int u = lu ^ (row & 15);
                gl2lds(A + (size_t)(m0 + row) * K + k0 + u * 8, dst + inst * 512);
            } else {
                const int bi = inst - 8;
                const int row = bi * 4 + lrow;              // B row 0..63
                const int u = lu ^ (row & 15);
                gl2lds(Wt + (size_t)(n0 + row) * K + k0 + u * 8,
                       dst + 32 * 128 + bi * 512);
            }
        }
    };

    const int kbyte = wid * 64;                     // this wave's k-slice (bytes)
    auto rdfrag = [&](const ushort_t* t, int row) -> bf16x8 {
        const int off0 = kbyte + l4 * 8;
        const int off1 = kbyte + 32 + l4 * 8;
        const int a0 = row * 256 + (((off0 & ~15) ^ ((row & 15) << 4)) | (off0 & 15));
        const int a1 = row * 256 + (((off1 & ~15) ^ ((row & 15) << 4)) | (off1 & 15));
        bf16x4 lo = *(const bf16x4*)((const char*)t + a0);
        bf16x4 hi = *(const bf16x4*)((const char*)t + a1);
        return __builtin_shufflevector(lo, hi, 0, 1, 2, 3, 4, 5, 6, 7);
    };

    stage(0, 0);
    __syncthreads();
    int cur = 0;
    for (int t = 0; t < niter; ++t) {
        if (t + 1 < niter) stage(cur ^ 1, (t + 1) << 7);
        const ushort_t* As = &smem[cur][0];
        const ushort_t* Bs = &smem[cur][32 * 128];
        bf16x8 af[2], bf[4];
#pragma unroll
        for (int m = 0; m < 2; ++m) af[m] = rdfrag(As, m * 16 + l15);
#pragma unroll
        for (int n = 0; n < 4; ++n) bf[n] = rdfrag(Bs, n * 16 + l15);
#pragma unroll
        for (int m = 0; m < 2; ++m)
#pragma unroll
            for (int n = 0; n < 4; ++n)
                acc[m][n] = __builtin_amdgcn_mfma_f32_16x16x32_bf16(af[m], bf[n], acc[m][n], 0, 0, 0);
        __syncthreads();
        cur ^= 1;
    }

    // ---- cross-wave reduce: waves 2,3 write; waves 0,1 accumulate ----
    float* cb0 = (float*)&smem[0][0];               // 32 x CL
    float* cb1 = (float*)&smem[1][0];
    if (wid >= 2) {
        float* cb = (wid == 2) ? cb0 : cb1;
#pragma unroll
        for (int m = 0; m < 2; ++m)
#pragma unroll
            for (int n = 0; n < 4; ++n)
#pragma unroll
                for (int r = 0; r < 4; ++r)
                    cb[(m * 16 + l4 * 4 + r) * CL + n * 16 + l15] = acc[m][n][r];
    }
    __syncthreads();
    if (wid < 2) {
        float* cb = (wid == 0) ? cb0 : cb1;
#pragma unroll
        for (int m = 0; m < 2; ++m)
#pragma unroll
            for (int n = 0; n < 4; ++n)
#pragma unroll
                for (int r = 0; r < 4; ++r)
                    cb[(m * 16 + l4 * 4 + r) * CL + n * 16 + l15] += acc[m][n][r];
    }
    __syncthreads();

    // ---- epilogue: thread t -> row t>>3, cols (t&7)*8 .. +7 ----
    const int row = tid >> 3, c0 = (tid & 7) * 8;
    const int grow = m0 + row;
#pragma unroll
    for (int j = 0; j < 8; ++j) {
        const int gcol = n0 + c0 + j;
        float v = cb0[row * CL + c0 + j] + cb1[row * CL + c0 + j] + bias[gcol];
        if (ACT == 1) v = v >= 0.f ? v : 0.01f * v;
        else if (ACT == 2) v = fmaxf(v, 0.f);
        else if (ACT == 3) {
            const int t2 = grow % T_SEQ;
            const float mv = (t2 < CTXF || t2 == T_SEQ - 1) ? 1.0f : 0.0f;
            v = res[(size_t)grow * N + gcol] * mv + v * (1.0f - mv);
        }
        if (PE) v += pe15[((grow % T_SEQ) % PERIODN) * DMODEL + gcol];
        if (RES) v += res[(size_t)grow * N + gcol];
        if (OUTBF) ((ushort_t*)Cout)[(size_t)grow * N + gcol] = f2bf(v);
        else       ((float*)Cout)[(size_t)grow * N + gcol] = v;
    }
}

// ---------------------------------------------------------------------------
// LayerNorm: f32 in, bf16 out. One wave per row.
// ---------------------------------------------------------------------------
__global__ __launch_bounds__(256)
void ln_k(const float* __restrict__ X, const float* __restrict__ g,
          const float* __restrict__ b, ushort_t* __restrict__ Y) {
    const int wid = threadIdx.x >> 6, lane = threadIdx.x & 63;
    const int row = blockIdx.x * 4 + wid;
    const float* x = X + (size_t)row * DMODEL;
    float v[8], s = 0.f;
#pragma unroll
    for (int j = 0; j < 8; ++j) { v[j] = x[lane + 64 * j]; s += v[j]; }
#pragma unroll
    for (int o = 32; o; o >>= 1) s += __shfl_xor(s, o);
    const float mean = s * (1.0f / DMODEL);
    float vs = 0.f;
#pragma unroll
    for (int j = 0; j < 8; ++j) { float d = v[j] - mean; vs += d * d; }
#pragma unroll
    for (int o = 32; o; o >>= 1) vs += __shfl_xor(vs, o);
    const float inv = rsqrtf(vs * (1.0f / DMODEL) + 1e-5f);
    ushort_t* y = Y + (size_t)row * DMODEL;
#pragma unroll
    for (int j = 0; j < 8; ++j) {
        const int c = lane + 64 * j;
        y[c] = f2bf((v[j] - mean) * inv * g[c] + b[c]);
    }
}

// ---------------------------------------------------------------------------
// V-mean partials: grid (16 bh, 8 chunks), 1024 thr. 192 rows per block.
// ---------------------------------------------------------------------------
__global__ __launch_bounds__(1024)
void vmeanp_k(const ushort_t* __restrict__ qkv, float* __restrict__ vmp) {
    __shared__ float red[16][64];
    const int bh = blockIdx.x, ch = blockIdx.y;
    const int b = bh >> 3, h = bh & 7;
    const int wid = threadIdx.x >> 6, lane = threadIdx.x & 63;
    const ushort_t* Vb = qkv + (size_t)(b * T_SEQ) * 1536 + 1024 + h * 64 + lane;
    float s = 0.f;
    const int t0 = ch * 192;
    for (int t = t0 + wid; t < t0 + 192; t += 16) s += bf2f(Vb[(size_t)t * 1536]);
    red[wid][lane] = s;
    __syncthreads();
    if (wid == 0) {
        float tot = 0.f;
#pragma unroll
        for (int i = 0; i < 16; ++i) tot += red[i][lane];
        vmp[(ch * 16 + bh) * 64 + lane] = tot;
    }
}

// Reduce 8 partials -> vm[1024] (= [b][h][d]), scaled by 1/T.
__global__ __launch_bounds__(1024)
void vmred_k(const float* __restrict__ vmp, float* __restrict__ vm) {
    const int t = threadIdx.x;
    float s = 0.f;
#pragma unroll
    for (int ch = 0; ch < 8; ++ch) s += vmp[ch * 1024 + t];
    vm[t] = s * (1.0f / T_SEQ);
}

// Fill inactive rows [q0, q0+grid.x) with vmean.
__global__ __launch_bounds__(256)
void vfill_k(const float* __restrict__ vm, ushort_t* __restrict__ attout, int q0) {
    const int qrow = q0 + blockIdx.x, b = blockIdx.y;
    const int tid = threadIdx.x;
#pragma unroll
    for (int r = 0; r < 2; ++r) {
        const int c = tid + r * 256;
        attout[(size_t)(b * T_SEQ + qrow) * DMODEL + c] = f2bf(vm[b * 512 + c]);
    }
}

// ---------------------------------------------------------------------------
// MFMA flash attention (round-9 proven). One WAVE per 16-row q-subtile.
// Swapped operands: S^T = mfma(K,Q) -> q = lane&15; O^T = mfma(V^T, P).
// ---------------------------------------------------------------------------
#define KLD 72
#define VLD 36
__global__ __launch_bounds__(256)
void attn3_k(const ushort_t* __restrict__ qkv, ushort_t* __restrict__ attout,
             int lo, int hi, int nlow, int qhi0, int tl, int st) {
    __shared__ ushort_t klds_[4][32 * KLD];
    __shared__ ushort_t vlds_[4][64 * VLD];
    const int lane = threadIdx.x & 63, wid = threadIdx.x >> 6;
    const int s = blockIdx.x * 4 + wid;
    if (s >= st) return;
    const int h = blockIdx.y, b = blockIdx.z;
    const int l15 = lane & 15, l4 = lane >> 4;

    int qb, qend;
    if (s < tl) { qb = 16 * s;                qend = nlow - 1; }
    else        { qb = qhi0 + 16 * (s - tl);  qend = T_SEQ - 1; }
    const int nr = qend - qb;

    ushort_t* klds = klds_[wid];
    ushort_t* vlds = vlds_[wid];
    const size_t rbase = (size_t)(b * T_SEQ) * 1536;
    const int q = qb + l15;

    const int qrow_r = min(q, T_SEQ - 1);
    const ushort_t* qptr = qkv + rbase + (size_t)qrow_r * 1536 + h * 64;
    bf16x8 bq[2];
#pragma unroll
    for (int kh = 0; kh < 2; ++kh) {
        bf16x4 lo4 = *(const bf16x4*)(qptr + kh * 32 + l4 * 4);
        bf16x4 hi4 = *(const bf16x4*)(qptr + kh * 32 + 16 + l4 * 4);
        bq[kh] = __builtin_shufflevector(lo4, hi4, 0, 1, 2, 3, 4, 5, 6, 7);
    }

    const int band0 = max(0, qb - THRW);
    const int band1 = min(T_SEQ - 1, qb + 15 + THRW);
    const int i1s = band0, i1e = min(band1, lo - 1);
    const int i2s = max(band0, hi), i2e = band1;

    f32x4 O[4] = {{0.f,0.f,0.f,0.f},{0.f,0.f,0.f,0.f},{0.f,0.f,0.f,0.f},{0.f,0.f,0.f,0.f}};
    float m = -3.0e38f, lsum = 0.f;

#pragma unroll 1
    for (int seg = 0; seg < 2; ++seg) {
        const int s0 = seg ? i2s : i1s, s1 = seg ? i2e : i1e;
#pragma unroll 1
        for (int c0 = s0; c0 <= s1; c0 += 32) {
#pragma unroll
            for (int i = 0; i < 4; ++i) {
                const int idx = i * 64 + lane;
                const int row = idx >> 3, c = (idx & 7) * 8;
                const int kr = min(c0 + row, T_SEQ - 1);
                const uint4 kv = *(const uint4*)(qkv + rbase + (size_t)kr * 1536 + 512 + h * 64 + c);
                *(uint4*)&klds[row * KLD + c] = kv;
                const uint4 vv = *(const uint4*)(qkv + rbase + (size_t)kr * 1536 + 1024 + h * 64 + c);
                const ushort_t* vp = (const ushort_t*)&vv;
#pragma unroll
                for (int d = 0; d < 8; ++d) vlds[(c + d) * VLD + row] = vp[d];
            }
            f32x4 sacc[2];
#pragma unroll
            for (int ks = 0; ks < 2; ++ks) {
                f32x4 a = {0.f, 0.f, 0.f, 0.f};
#pragma unroll
                for (int kh = 0; kh < 2; ++kh) {
                    const ushort_t* kp = &klds[(16 * ks + l15) * KLD + kh * 32];
                    bf16x4 lo4 = *(const bf16x4*)(kp + l4 * 4);
                    bf16x4 hi4 = *(const bf16x4*)(kp + 16 + l4 * 4);
                    bf16x8 ak = __builtin_shufflevector(lo4, hi4, 0, 1, 2, 3, 4, 5, 6, 7);
                    a = __builtin_amdgcn_mfma_f32_16x16x32_bf16(ak, bq[kh], a, 0, 0, 0);
                }
                sacc[ks] = a;
            }
            float sv[8];
            bool vld[8];
            float cm = -3.0e38f;
#pragma unroll
            for (int ks = 0; ks < 2; ++ks)
#pragma unroll
                for (int r = 0; r < 4; ++r) {
                    const int key = c0 + 16 * ks + 4 * l4 + r;
                    const int dist = (q > key) ? (q - key) : (key - q);
                    const bool v = (dist <= THRW) && (key < lo || key >= hi) && (key < T_SEQ);
                    const int ii = ks * 4 + r;
                    sv[ii] = sacc[ks][r] * 0.125f - (float)(dist / PERIODN);
                    vld[ii] = v;
                    cm = fmaxf(cm, v ? sv[ii] : -3.0e38f);
                }
            cm = fmaxf(cm, __shfl_xor(cm, 16));
            cm = fmaxf(cm, __shfl_xor(cm, 32));
            const float mnew = fmaxf(m, cm);
            const float sc = __expf(m - mnew);
            m = mnew;
            float p[8], psum = 0.f;
#pragma unroll
            for (int ii = 0; ii < 8; ++ii) {
                p[ii] = vld[ii] ? __expf(sv[ii] - mnew) : 0.f;
                psum += p[ii];
            }
            psum += __shfl_xor(psum, 16);
            psum += __shfl_xor(psum, 32);
            lsum = lsum * sc + psum;
#pragma unroll
            for (int ds = 0; ds < 4; ++ds) O[ds] *= sc;
            bf16x8 pb;
#pragma unroll
            for (int ii = 0; ii < 8; ++ii) pb[ii] = (__bf16)p[ii];
#pragma unroll
            for (int ds = 0; ds < 4; ++ds) {
                const ushort_t* vp2 = &vlds[(16 * ds + l15) * VLD];
                bf16x4 lo4 = *(const bf16x4*)(vp2 + 4 * l4);
                bf16x4 hi4 = *(const bf16x4*)(vp2 + 16 + 4 * l4);
                bf16x8 av = __builtin_shufflevector(lo4, hi4, 0, 1, 2, 3, 4, 5, 6, 7);
                O[ds] = __builtin_amdgcn_mfma_f32_16x16x32_bf16(av, pb, O[ds], 0, 0, 0);
            }
        }
    }
    if (l15 <= nr) {
        const float inv = 1.0f / lsum;
        ushort_t* op = attout + (size_t)(b * T_SEQ + qb + l15) * DMODEL + h * 64;
#pragma unroll
        for (int ds = 0; ds < 4; ++ds)
#pragma unroll
            for (int r = 0; r < 4; ++r)
                op[16 * ds + 4 * l4 + r] = f2bf(O[ds][r] * inv);
    }
}

// ---------------------------------------------------------------------------
extern "C" void kernel_launch(void* const* d_in, const int* in_sizes, int n_in,
                              void* d_out, int out_size, void* d_ws, size_t ws_size,
                              hipStream_t stream) {
    const float* motion = (const float*)d_in[0];
    const float* traj   = (const float*)d_in[1];
    const float* me_w1  = (const float*)d_in[2];
    const float* me_b1  = (const float*)d_in[3];
    const float* me_w2  = (const float*)d_in[4];
    const float* me_b2  = (const float*)d_in[5];
    const float* wq = (const float*)d_in[6];
    const float* bq = (const float*)d_in[7];
    const float* wk = (const float*)d_in[8];
    const float* bk = (const float*)d_in[9];
    const float* wv = (const float*)d_in[10];
    const float* bv = (const float*)d_in[11];
    const float* wo = (const float*)d_in[12];
    const float* bo = (const float*)d_in[13];
    const float* ln1_g = (const float*)d_in[14];
    const float* ln1_b = (const float*)d_in[15];
    const float* ffn_w1 = (const float*)d_in[16];
    const float* ffn_b1 = (const float*)d_in[17];
    const float* ffn_w2 = (const float*)d_in[18];
    const float* ffn_b2 = (const float*)d_in[19];
    const float* ln2_g = (const float*)d_in[20];
    const float* ln2_b = (const float*)d_in[21];
    const float* fln_g = (const float*)d_in[22];
    const float* fln_b = (const float*)d_in[23];
    const float* dec_w1 = (const float*)d_in[24];
    const float* dec_b1 = (const float*)d_in[25];
    const float* dec_w2 = (const float*)d_in[26];
    const float* dec_b2 = (const float*)d_in[27];

    float* out = (float*)d_out;
    float* mask_out = out + (size_t)MROWS * DMOTION;

    char* base = (char*)d_ws;
    auto alloc = [&](size_t bytes) { char* p = base; base += (bytes + 255) & ~(size_t)255; return p; };

    ushort_t* qkvt  = (ushort_t*)alloc((size_t)NLAYERS * 1536 * 512 * 2);
    ushort_t* wot   = (ushort_t*)alloc((size_t)NLAYERS * 512 * 512 * 2);
    ushort_t* ffn1t = (ushort_t*)alloc((size_t)NLAYERS * 2048 * 512 * 2);
    ushort_t* ffn2t = (ushort_t*)alloc((size_t)NLAYERS * 512 * 2048 * 2);
    ushort_t* mew1t = (ushort_t*)alloc((size_t)512 * KIN * 2);
    ushort_t* mew2t = (ushort_t*)alloc((size_t)512 * 512 * 2);
    ushort_t* dec1t = (ushort_t*)alloc((size_t)512 * 512 * 2);
    ushort_t* dec2t = (ushort_t*)alloc((size_t)256 * 512 * 2);
    float*    bqkv  = (float*)alloc((size_t)NLAYERS * 1536 * 4);
    float*    pe15  = (float*)alloc((size_t)PERIODN * DMODEL * 4);
    float*    vmp   = (float*)alloc((size_t)8 * 16 * 64 * 4);
    float*    vm    = (float*)alloc((size_t)16 * 64 * 4);
    ushort_t* hin   = (ushort_t*)alloc((size_t)MROWS * KIN * 2);
    float*    x     = (float*)alloc((size_t)MROWS * DMODEL * 4);
    ushort_t* h     = (ushort_t*)alloc((size_t)MROWS * DMODEL * 2);
    ushort_t* qkv   = (ushort_t*)alloc((size_t)MROWS * 1536 * 2);
    ushort_t* ff    = (ushort_t*)alloc((size_t)MROWS * DFF * 2);

    const dim3 blk(256);
    pe_k<<<(PERIODN * DMODEL + 255) / 256, blk, 0, stream>>>(pe15);
    build_k<<<(MROWS * KIN + 255) / 256, blk, 0, stream>>>(motion, traj, hin, mask_out);

    tconv_qkv_k<<<dim3(16, 16, 18), blk, 0, stream>>>(wq, wk, wv, qkvt);
    tconv_k<<<dim3(16, 16, 6), blk, 0, stream>>>(wo, 512 * 512, wot, 512 * 512, 512, 512, 512);
    tconv_k<<<dim3(64, 16, 6), blk, 0, stream>>>(ffn_w1, 512 * 2048, ffn1t, 2048 * 512, 512, 2048, 512);
    tconv_k<<<dim3(16, 64, 6), blk, 0, stream>>>(ffn_w2, 2048 * 512, ffn2t, 512 * 2048, 2048, 512, 2048);
    tconv_k<<<dim3(16, 12, 1), blk, 0, stream>>>(me_w1, 0, mew1t, 0, 262, 512, KIN);
    tconv_k<<<dim3(16, 16, 1), blk, 0, stream>>>(me_w2, 0, mew2t, 0, 512, 512, 512);
    tconv_k<<<dim3(16, 16, 1), blk, 0, stream>>>(dec_w1, 0, dec1t, 0, 512, 512, 512);
    tconv_k<<<dim3(8, 16, 1),  blk, 0, stream>>>(dec_w2, 0, dec2t, 0, 512, 256, 512);
    bcat_k<<<(NLAYERS * 1536 + 255) / 256, blk, 0, stream>>>(bq, bk, bv, bqkv);

    const dim3 gs512(8, 96), gs1536(24, 96), gsff(32, 96), gs256(4, 96);

    // motion encoder
    qgemm_k<1, false, false, true ><<<gs512, blk, 0, stream>>>(hin, KIN, mew1t, me_b1, nullptr, nullptr, h, 512);
    qgemm_k<1, false, true,  false><<<gs512, blk, 0, stream>>>(h, 512, mew2t, me_b2, nullptr, pe15, x, 512);

    for (int i = 0; i < NLAYERS; ++i) {
        const int lo = CTXF + THRW * i;
        const int hi = (T_SEQ - 1) - THRW * i;
        int qlow_end = lo + 127;
        int qhi0 = hi - 128;
        int nlow, ninact;
        if (qhi0 <= qlow_end + 1) {
            nlow = T_SEQ; qhi0 = T_SEQ; ninact = 0;
        } else {
            nlow = qlow_end + 1;
            ninact = qhi0 - nlow;
        }
        const int tl2 = (nlow + 15) / 16;
        const int th2 = (T_SEQ - qhi0 + 15) / 16;
        const int st  = tl2 + th2;

        ln_k<<<MROWS / 4, blk, 0, stream>>>(x, ln1_g + i * 512, ln1_b + i * 512, h);
        qgemm_k<0, false, false, true><<<gs1536, blk, 0, stream>>>(h, 512, qkvt + (size_t)i * 1536 * 512, bqkv + i * 1536, nullptr, nullptr, qkv, 1536);
        if (ninact > 0) {
            vmeanp_k<<<dim3(16, 8), dim3(1024), 0, stream>>>(qkv, vmp);
            vmred_k<<<1, dim3(1024), 0, stream>>>(vmp, vm);
            vfill_k<<<dim3(ninact, NB), blk, 0, stream>>>(vm, h, nlow);
        }
        attn3_k<<<dim3((st + 3) / 4, NHEADS, NB), blk, 0, stream>>>(qkv, h, lo, hi, nlow, qhi0, tl2, st);
        qgemm_k<0, true, false, false><<<gs512, blk, 0, stream>>>(h, 512, wot + (size_t)i * 512 * 512, bo + i * 512, x, nullptr, x, 512);
        ln_k<<<MROWS / 4, blk, 0, stream>>>(x, ln2_g + i * 512, ln2_b + i * 512, h);
        qgemm_k<2, false, false, true><<<gsff, blk, 0, stream>>>(h, 512, ffn1t + (size_t)i * 2048 * 512, ffn_b1 + i * 2048, nullptr, nullptr, ff, 2048);
        qgemm_k<0, true, false, false><<<gs512, blk, 0, stream>>>(ff, 2048, ffn2t + (size_t)i * 512 * 2048, ffn_b2 + i * 512, x, nullptr, x, 512);
    }

    // decoder: dec1 (leaky) -> dec2 fused with final blend (ACT=3, res=motion)
    ln_k<<<MROWS / 4, blk, 0, stream>>>(x, fln_g, fln_b, h);
    qgemm_k<1, false, false, true ><<<gs512, blk, 0, stream>>>(h, 512, dec1t, dec_b1, nullptr, nullptr, ff, 512);
    qgemm_k<3, false, false, false><<<gs256, blk, 0, stream>>>(ff, 512, dec2t, dec_b2, motion, nullptr, out, 256);
}